// Round 2
// baseline (269.124 us; speedup 1.0000x reference)
//
#include <hip/hip_runtime.h>
#include <math.h>

namespace {
constexpr int kB = 4;
constexpr int kS = 4096;
constexpr int kH = 4096;
constexpr int kE = 16;
constexpr int kTokens = kB * kS;            // 16384
constexpr int kT = 4;                       // tokens per wave
constexpr int kWavesPerBlock = 4;
constexpr int kBlockThreads = 64 * kWavesPerBlock;      // 256
constexpr int kTokensPerBlock = kT * kWavesPerBlock;    // 16
constexpr int kGrid = kTokens / kTokensPerBlock;        // 1024
constexpr int kChunk = 256;                 // floats of H per pipeline stage
constexpr int kNChunks = kH / kChunk;       // 16
}  // namespace

__device__ __forceinline__ void stage_w_row(const float* src_lane,
                                            const float* lds_row_base) {
  // wave-uniform LDS base; HW adds lane*16. Linear dest + linear src (no swizzle).
  __builtin_amdgcn_global_load_lds(
      (const __attribute__((address_space(1))) void*)src_lane,
      (__attribute__((address_space(3))) void*)lds_row_base, 16, 0, 0);
}

// Gate GEMM (W staged via LDS double-buffer, x prefetched in regs) + softmax +
// top-2 + aux partials.
__global__ __launch_bounds__(kBlockThreads, 4) void router_main(
    const float* __restrict__ x, const float* __restrict__ W,
    float* __restrict__ out_probs,   // [kTokens][2]
    float* __restrict__ out_idx,     // [kTokens][2] (indices as float)
    float* __restrict__ gsum) {      // [2*kE]: counts[16], probsum[16]
  __shared__ float s_w[2][kE][kChunk];     // 2 x 16 KB
  __shared__ float s_cnt[kE];
  __shared__ float s_psum[kE];

  const int tid = threadIdx.x;
  if (tid < kE) { s_cnt[tid] = 0.f; s_psum[tid] = 0.f; }

  const int wave = tid >> 6;
  const int lane = tid & 63;
  const int tok0 = (blockIdx.x * kWavesPerBlock + wave) * kT;
  const float* xrow = x + (size_t)tok0 * kH;

  float acc[kT][kE];
#pragma unroll
  for (int t = 0; t < kT; ++t)
#pragma unroll
    for (int e = 0; e < kE; ++e) acc[t][e] = 0.f;

  // Prologue: stage chunk 0 into buf 0; prefetch x chunk 0 into regs.
#pragma unroll
  for (int i = 0; i < 4; ++i) {
    const int e = wave * 4 + i;
    stage_w_row(W + (size_t)e * kH + lane * 4, &s_w[0][e][0]);
  }
  float4 xv_cur[kT];
#pragma unroll
  for (int t = 0; t < kT; ++t)
    xv_cur[t] = *reinterpret_cast<const float4*>(xrow + (size_t)t * kH + lane * 4);
  __syncthreads();   // drains vmcnt(0): stage(0) + xv_cur resident everywhere

  for (int j = 0; j < kNChunks; ++j) {
    const int cur = j & 1;
    float4 xv_next[kT];
    if (j + 1 < kNChunks) {
      const int joff = (j + 1) * kChunk;
      // stage W chunk j+1 into the other buffer (issue only; no wait here)
#pragma unroll
      for (int i = 0; i < 4; ++i) {
        const int e = wave * 4 + i;
        stage_w_row(W + (size_t)e * kH + joff + lane * 4, &s_w[cur ^ 1][e][0]);
      }
      // prefetch x chunk j+1 (issue only)
#pragma unroll
      for (int t = 0; t < kT; ++t)
        xv_next[t] = *reinterpret_cast<const float4*>(
            xrow + (size_t)t * kH + joff + lane * 4);
    }

    // Compute chunk j: W from LDS (ds_read_b128, conflict-free), x from regs.
#pragma unroll
    for (int e = 0; e < kE; ++e) {
      const float4 wv = *reinterpret_cast<const float4*>(&s_w[cur][e][lane * 4]);
#pragma unroll
      for (int t = 0; t < kT; ++t) {
        acc[t][e] = fmaf(xv_cur[t].x, wv.x, acc[t][e]);
        acc[t][e] = fmaf(xv_cur[t].y, wv.y, acc[t][e]);
        acc[t][e] = fmaf(xv_cur[t].z, wv.z, acc[t][e]);
        acc[t][e] = fmaf(xv_cur[t].w, wv.w, acc[t][e]);
      }
    }

    __syncthreads();   // barrier + full mem drain: stage(j+1)/xv_next complete,
                       // and no wave still reads buf cur^1 when next overwrite
#pragma unroll
    for (int t = 0; t < kT; ++t) xv_cur[t] = xv_next[t];
  }

  // Butterfly reduction: every lane ends with full sums for its wave's tokens.
#pragma unroll
  for (int off = 1; off < 64; off <<= 1) {
#pragma unroll
    for (int t = 0; t < kT; ++t)
#pragma unroll
      for (int e = 0; e < kE; ++e)
        acc[t][e] += __shfl_xor(acc[t][e], off, 64);
  }

  // Lanes 0..kT-1 each finish one token.
  if (lane < kT) {
    const int tok = tok0 + lane;
    float l[kE];
#pragma unroll
    for (int e = 0; e < kE; ++e) l[e] = acc[lane][e];

    float m = l[0];
#pragma unroll
    for (int e = 1; e < kE; ++e) m = fmaxf(m, l[e]);
    float p[kE];
    float s = 0.f;
#pragma unroll
    for (int e = 0; e < kE; ++e) { p[e] = __expf(l[e] - m); s += p[e]; }
    const float inv = 1.f / s;
#pragma unroll
    for (int e = 0; e < kE; ++e) p[e] *= inv;

    // top-2 on probs (reference: top_k AFTER softmax; ties -> lowest index)
    int i1 = 0;
    float v1 = p[0];
#pragma unroll
    for (int e = 1; e < kE; ++e)
      if (p[e] > v1) { v1 = p[e]; i1 = e; }
    int i2 = (i1 == 0) ? 1 : 0;
    float v2 = p[i2];
#pragma unroll
    for (int e = 0; e < kE; ++e) {
      if (e == i1) continue;
      if (p[e] > v2) { v2 = p[e]; i2 = e; }
    }

    const float ns = 1.f / (v1 + v2);
    out_probs[tok * 2 + 0] = v1 * ns;
    out_probs[tok * 2 + 1] = v2 * ns;
    out_idx[tok * 2 + 0] = (float)i1;
    out_idx[tok * 2 + 1] = (float)i2;

#pragma unroll
    for (int e = 0; e < kE; ++e) atomicAdd(&s_psum[e], p[e]);
    atomicAdd(&s_cnt[i1], 1.f);
    atomicAdd(&s_cnt[i2], 1.f);
  }
  __syncthreads();
  if (tid < kE) {
    atomicAdd(&gsum[tid], s_cnt[tid]);          // counts
    atomicAdd(&gsum[kE + tid], s_psum[tid]);    // prob sums
  }
}

// aux_loss = E * sum_e (count_e / B) * (probsum_e / (B*S))
__global__ void aux_finish(const float* __restrict__ gsum, float* __restrict__ out_aux) {
  if (threadIdx.x == 0 && blockIdx.x == 0) {
    double acc = 0.0;
    for (int e = 0; e < kE; ++e)
      acc += (double)gsum[e] * (double)gsum[kE + e];
    out_aux[0] = (float)(acc * (double)kE / ((double)kB * (double)kB * (double)kS));
  }
}

extern "C" void kernel_launch(void* const* d_in, const int* in_sizes, int n_in,
                              void* d_out, int out_size, void* d_ws, size_t ws_size,
                              hipStream_t stream) {
  const float* x = (const float*)d_in[0];   // [B,S,H] f32
  const float* W = (const float*)d_in[1];   // [E,H]   f32
  float* out = (float*)d_out;               // [32768 probs][32768 idx][1 aux]
  float* gsum = (float*)d_ws;

  hipMemsetAsync(d_ws, 0, 2 * kE * sizeof(float), stream);
  router_main<<<kGrid, kBlockThreads, 0, stream>>>(
      x, W, out, out + 2 * kTokens, gsum);
  aux_finish<<<1, 64, 0, stream>>>(gsum, out + 4 * kTokens);
}

// Round 3
// 111.617 us; speedup vs baseline: 2.4111x; 2.4111x over previous
//
#include <hip/hip_runtime.h>
#include <math.h>

namespace {
constexpr int kB = 4;
constexpr int kS = 4096;
constexpr int kH = 4096;
constexpr int kE = 16;
constexpr int kTokens = kB * kS;            // 16384
constexpr int kT = 4;                       // tokens per wave (compute)
constexpr int kEW = 8;                      // experts per wave (e-split)
constexpr int kWavesPerBlock = 4;
constexpr int kBlockThreads = 64 * kWavesPerBlock;   // 256
constexpr int kTokBlk = 8;                  // tokens per block (2 token-groups)
constexpr int kGrid = kTokens / kTokBlk;    // 2048
constexpr int kChunk = 256;                 // floats of H per pipeline stage (1 KB/row)
constexpr int kNC = kH / kChunk;            // 16
}  // namespace

__device__ __forceinline__ void gload_lds16(const float* src_lane, float* lds_base) {
  // wave-uniform LDS base; HW adds lane*16. Linear dest + linear src.
  __builtin_amdgcn_global_load_lds(
      (const __attribute__((address_space(1))) void*)src_lane,
      (__attribute__((address_space(3))) void*)lds_base, 16, 0, 0);
}

// Gate GEMM with BOTH operands LDS-staged (near-zero register staging cost),
// experts split across wave pairs so acc[4][8] = 32 VGPRs. Softmax + top-2 +
// aux partials in a tiny epilogue.
__global__ __launch_bounds__(kBlockThreads) void router_main(
    const float* __restrict__ x, const float* __restrict__ W,
    float* __restrict__ out_probs,   // [kTokens][2]
    float* __restrict__ out_idx,     // [kTokens][2] (indices as float)
    float* __restrict__ gsum) {      // [2*kE]: counts[16], probsum[16]
  __shared__ float s_w[2][kE][kChunk];       // 32 KB
  __shared__ float s_x[2][kTokBlk][kChunk];  // 16 KB
  __shared__ float s_logit[kTokBlk][kE];
  __shared__ float s_cnt[kE];
  __shared__ float s_psum[kE];

  const int tid = threadIdx.x;
  const int wave = tid >> 6;
  const int lane = tid & 63;
  const int tg = wave >> 1;                 // token group: 0 -> tokens 0-3, 1 -> 4-7
  const int eo = (wave & 1) * kEW;          // expert offset: 0 or 8
  const int tokBase = blockIdx.x * kTokBlk;

  if (tid < kE) { s_cnt[tid] = 0.f; s_psum[tid] = 0.f; }

  // Stage chunk j into buffer buf: whole block covers W[16][chunk] + x[8][chunk].
  // Each wave: 4 W rows + 2 x rows, one global_load_lds (width 16) per row.
  auto stage = [&](int buf, int j) {
    const int off = j * kChunk + lane * 4;
#pragma unroll
    for (int i = 0; i < 4; ++i) {
      const int e = wave * 4 + i;
      gload_lds16(W + (size_t)e * kH + off, &s_w[buf][e][0]);
    }
#pragma unroll
    for (int i = 0; i < 2; ++i) {
      const int t = wave * 2 + i;
      gload_lds16(x + (size_t)(tokBase + t) * kH + off, &s_x[buf][t][0]);
    }
  };

  float acc[kT][kEW];
#pragma unroll
  for (int t = 0; t < kT; ++t)
#pragma unroll
    for (int e = 0; e < kEW; ++e) acc[t][e] = 0.f;

  stage(0, 0);
  __syncthreads();   // vmcnt drain: chunk 0 resident

  for (int j = 0; j < kNC; ++j) {
    const int buf = j & 1;
    if (j + 1 < kNC) stage(buf ^ 1, j + 1);   // issue only; drains at barrier

    float4 xv[kT];
#pragma unroll
    for (int t = 0; t < kT; ++t)
      xv[t] = *reinterpret_cast<const float4*>(&s_x[buf][tg * kT + t][lane * 4]);
#pragma unroll
    for (int e = 0; e < kEW; ++e) {
      const float4 wv =
          *reinterpret_cast<const float4*>(&s_w[buf][eo + e][lane * 4]);
#pragma unroll
      for (int t = 0; t < kT; ++t) {
        acc[t][e] = fmaf(xv[t].x, wv.x, acc[t][e]);
        acc[t][e] = fmaf(xv[t].y, wv.y, acc[t][e]);
        acc[t][e] = fmaf(xv[t].z, wv.z, acc[t][e]);
        acc[t][e] = fmaf(xv[t].w, wv.w, acc[t][e]);
      }
    }
    __syncthreads();   // stage(j+1) complete; no wave still reads old buffer
  }

  // Butterfly: every lane ends with full-H sums for its wave's 4x8 tile.
#pragma unroll
  for (int off = 1; off < 64; off <<= 1) {
#pragma unroll
    for (int t = 0; t < kT; ++t)
#pragma unroll
      for (int e = 0; e < kEW; ++e)
        acc[t][e] += __shfl_xor(acc[t][e], off, 64);
  }

  // Lanes 0..3 of each wave publish their token's 8-expert slice.
  if (lane < kT) {
    const int r = tg * kT + lane;
#pragma unroll
    for (int e = 0; e < kEW; ++e) s_logit[r][eo + e] = acc[lane][e];
  }
  __syncthreads();

  // Wave 0, lanes 0..7: one token each — softmax, top-2, outputs, aux partials.
  if (wave == 0 && lane < kTokBlk) {
    const int tok = tokBase + lane;
    float l[kE];
#pragma unroll
    for (int e = 0; e < kE; ++e) l[e] = s_logit[lane][e];

    float m = l[0];
#pragma unroll
    for (int e = 1; e < kE; ++e) m = fmaxf(m, l[e]);
    float p[kE];
    float s = 0.f;
#pragma unroll
    for (int e = 0; e < kE; ++e) { p[e] = __expf(l[e] - m); s += p[e]; }
    const float inv = 1.f / s;
#pragma unroll
    for (int e = 0; e < kE; ++e) p[e] *= inv;

    // top-2 on probs (reference: top_k AFTER softmax; ties -> lowest index)
    int i1 = 0;
    float v1 = p[0];
#pragma unroll
    for (int e = 1; e < kE; ++e)
      if (p[e] > v1) { v1 = p[e]; i1 = e; }
    int i2 = (i1 == 0) ? 1 : 0;
    float v2 = p[i2];
#pragma unroll
    for (int e = 0; e < kE; ++e) {
      if (e == i1) continue;
      if (p[e] > v2) { v2 = p[e]; i2 = e; }
    }

    const float ns = 1.f / (v1 + v2);
    out_probs[tok * 2 + 0] = v1 * ns;
    out_probs[tok * 2 + 1] = v2 * ns;
    out_idx[tok * 2 + 0] = (float)i1;
    out_idx[tok * 2 + 1] = (float)i2;

#pragma unroll
    for (int e = 0; e < kE; ++e) atomicAdd(&s_psum[e], p[e]);
    atomicAdd(&s_cnt[i1], 1.f);
    atomicAdd(&s_cnt[i2], 1.f);
  }
  __syncthreads();
  if (tid < kE) {
    atomicAdd(&gsum[tid], s_cnt[tid]);          // counts
    atomicAdd(&gsum[kE + tid], s_psum[tid]);    // prob sums
  }
}

// aux_loss = E * sum_e (count_e / B) * (probsum_e / (B*S))
__global__ void aux_finish(const float* __restrict__ gsum, float* __restrict__ out_aux) {
  if (threadIdx.x == 0 && blockIdx.x == 0) {
    double acc = 0.0;
    for (int e = 0; e < kE; ++e)
      acc += (double)gsum[e] * (double)gsum[kE + e];
    out_aux[0] = (float)(acc * (double)kE / ((double)kB * (double)kB * (double)kS));
  }
}

extern "C" void kernel_launch(void* const* d_in, const int* in_sizes, int n_in,
                              void* d_out, int out_size, void* d_ws, size_t ws_size,
                              hipStream_t stream) {
  const float* x = (const float*)d_in[0];   // [B,S,H] f32
  const float* W = (const float*)d_in[1];   // [E,H]   f32
  float* out = (float*)d_out;               // [32768 probs][32768 idx][1 aux]
  float* gsum = (float*)d_ws;

  hipMemsetAsync(d_ws, 0, 2 * kE * sizeof(float), stream);
  router_main<<<kGrid, kBlockThreads, 0, stream>>>(
      x, W, out, out + 2 * kTokens, gsum);
  aux_finish<<<1, 64, 0, stream>>>(gsum, out + 4 * kTokens);
}

// Round 4
// 107.958 us; speedup vs baseline: 2.4929x; 1.0339x over previous
//
#include <hip/hip_runtime.h>
#include <math.h>

namespace {
constexpr int kB = 4;
constexpr int kS = 4096;
constexpr int kH = 4096;
constexpr int kE = 16;
constexpr int kTokens = kB * kS;            // 16384
constexpr int kT = 4;                       // tokens per wave tile
constexpr int kEW = 8;                      // experts per wave tile
constexpr int kThreads = 512;               // 8 waves
constexpr int kTokBlk = 16;                 // tokens per block
constexpr int kGrid = kTokens / kTokBlk;    // 1024
constexpr int kChunk = 128;                 // floats of H per pipeline stage (512 B/row)
constexpr int kNC = kH / kChunk;            // 32
constexpr int kRing = 4;                    // LDS ring depth; staged 3 ahead
}  // namespace

__device__ __forceinline__ void gload_lds16(const float* src_lane, float* lds_base) {
  // wave-uniform LDS base; HW adds lane*16. Linear dest + per-lane global src.
  __builtin_amdgcn_global_load_lds(
      (const __attribute__((address_space(1))) void*)src_lane,
      (__attribute__((address_space(3))) void*)lds_base, 16, 0, 0);
}

// Gate GEMM: both operands LDS-staged through a 4-deep ring with counted-vmcnt
// barriers (T3/T4) so HBM latency is never exposed at a drain. Softmax + top-2
// + per-block aux partials in the epilogue.
__global__ __launch_bounds__(kThreads) void router_main(
    const float* __restrict__ x, const float* __restrict__ W,
    float* __restrict__ out_probs,   // [kTokens][2]
    float* __restrict__ out_idx,     // [kTokens][2] (indices as float)
    float* __restrict__ gpart) {     // [kGrid][32]: cnt[16], psum[16] per block
  __shared__ float s_w[kRing][kE][kChunk];       // 32 KB
  __shared__ float s_x[kRing][kTokBlk][kChunk];  // 32 KB
  __shared__ float s_logit[kTokBlk][kE];
  __shared__ float s_cnt[kE];
  __shared__ float s_psum[kE];

  const int tid = threadIdx.x;
  const int wave = tid >> 6;
  const int lane = tid & 63;
  const int tg = wave >> 1;                 // token group 0..3 -> tokens tg*4..+3
  const int eo = (wave & 1) * kEW;          // expert offset 0 or 8
  const int tokBase = blockIdx.x * kTokBlk;

  if (tid < kE) { s_cnt[tid] = 0.f; s_psum[tid] = 0.f; }

  // Staging: each wave covers 2 W rows and 2 x rows per chunk with ONE
  // width-16 gload each (64 lanes x 16 B = 1 KB = two contiguous 512 B rows).
  const int half = lane >> 5;               // row within the pair
  const int lc = (lane & 31) * 4;           // float offset within the row
  auto stage = [&](int buf, int j) {
    const size_t goff = (size_t)j * kChunk + lc;
    gload_lds16(W + (size_t)(2 * wave + half) * kH + goff, &s_w[buf][2 * wave][0]);
    gload_lds16(x + (size_t)(tokBase + 2 * wave + half) * kH + goff,
                &s_x[buf][2 * wave][0]);
  };

  float acc[kT][kEW];
#pragma unroll
  for (int t = 0; t < kT; ++t)
#pragma unroll
    for (int e = 0; e < kEW; ++e) acc[t][e] = 0.f;

  // Prologue: 3 chunks in flight (6 loads/wave outstanding).
  stage(0, 0);
  stage(1, 1);
  stage(2, 2);

  for (int j = 0; j < kNC; ++j) {
    const int buf = j & (kRing - 1);

    // Counted wait: keep stages j+1, j+2 (4 loads) in flight across the
    // barrier; only chunk j's own 2 loads must have landed. (Tail peel.)
    if (j + 2 < kNC)      asm volatile("s_waitcnt vmcnt(4)" ::: "memory");
    else if (j + 1 < kNC) asm volatile("s_waitcnt vmcnt(2)" ::: "memory");
    else                  asm volatile("s_waitcnt vmcnt(0)" ::: "memory");
    __builtin_amdgcn_s_barrier();           // all waves' chunk-j stages done
    asm volatile("" ::: "memory");

    const int bx = lane * 2;                // float2 per lane: 2-way banks, free
    float2 xv[kT];
#pragma unroll
    for (int t = 0; t < kT; ++t)
      xv[t] = *reinterpret_cast<const float2*>(&s_x[buf][tg * kT + t][bx]);
#pragma unroll
    for (int e = 0; e < kEW; ++e) {
      const float2 wv = *reinterpret_cast<const float2*>(&s_w[buf][eo + e][bx]);
#pragma unroll
      for (int t = 0; t < kT; ++t) {
        acc[t][e] = fmaf(xv[t].x, wv.x, acc[t][e]);
        acc[t][e] = fmaf(xv[t].y, wv.y, acc[t][e]);
      }
    }

    asm volatile("" ::: "memory");
    __builtin_amdgcn_s_barrier();           // buffer j free for reuse
    asm volatile("" ::: "memory");
    if (j + 3 < kNC) stage((j + 3) & (kRing - 1), j + 3);
  }

  // Butterfly: every lane ends with full-H sums for its 4x8 tile.
#pragma unroll
  for (int off = 1; off < 64; off <<= 1) {
#pragma unroll
    for (int t = 0; t < kT; ++t)
#pragma unroll
      for (int e = 0; e < kEW; ++e)
        acc[t][e] += __shfl_xor(acc[t][e], off, 64);
  }

  // Lanes 0..3 of each wave publish their token's 8-expert slice.
  if (lane < kT) {
    const int r = tg * kT + lane;
#pragma unroll
    for (int e = 0; e < kEW; ++e) s_logit[r][eo + e] = acc[lane][e];
  }
  __syncthreads();

  // Wave 0, lanes 0..15: one token each — softmax, top-2, outputs, aux partials.
  if (wave == 0 && lane < kTokBlk) {
    const int tok = tokBase + lane;
    float l[kE];
#pragma unroll
    for (int e = 0; e < kE; ++e) l[e] = s_logit[lane][e];

    float m = l[0];
#pragma unroll
    for (int e = 1; e < kE; ++e) m = fmaxf(m, l[e]);
    float p[kE];
    float s = 0.f;
#pragma unroll
    for (int e = 0; e < kE; ++e) { p[e] = __expf(l[e] - m); s += p[e]; }
    const float inv = 1.f / s;
#pragma unroll
    for (int e = 0; e < kE; ++e) p[e] *= inv;

    // top-2 on probs (reference: top_k AFTER softmax; ties -> lowest index)
    int i1 = 0;
    float v1 = p[0];
#pragma unroll
    for (int e = 1; e < kE; ++e)
      if (p[e] > v1) { v1 = p[e]; i1 = e; }
    int i2 = (i1 == 0) ? 1 : 0;
    float v2 = p[i2];
#pragma unroll
    for (int e = 0; e < kE; ++e) {
      if (e == i1) continue;
      if (p[e] > v2) { v2 = p[e]; i2 = e; }
    }

    const float ns = 1.f / (v1 + v2);
    out_probs[tok * 2 + 0] = v1 * ns;
    out_probs[tok * 2 + 1] = v2 * ns;
    out_idx[tok * 2 + 0] = (float)i1;
    out_idx[tok * 2 + 1] = (float)i2;

#pragma unroll
    for (int e = 0; e < kE; ++e) atomicAdd(&s_psum[e], p[e]);
    atomicAdd(&s_cnt[i1], 1.f);
    atomicAdd(&s_cnt[i2], 1.f);
  }
  __syncthreads();
  // Per-block partials (coalesced store) instead of contended global atomics.
  if (tid < 2 * kE)
    gpart[(size_t)blockIdx.x * 2 * kE + tid] =
        (tid < kE) ? s_cnt[tid] : s_psum[tid - kE];
}

// Reduce per-block partials; aux = E * sum_e (cnt_e/B) * (psum_e/(B*S)).
__global__ __launch_bounds__(1024) void aux_finish(
    const float* __restrict__ gpart, float* __restrict__ out_aux) {
  __shared__ float s_red[32][32];
  __shared__ float s_final[32];
  const int tid = threadIdx.x;
  const int c = tid & 31;       // column: 0-15 cnt, 16-31 psum
  const int r0 = tid >> 5;      // row-slice 0..31
  float s = 0.f;
  for (int k = 0; k < kGrid / 32; ++k)
    s += gpart[(size_t)(r0 * (kGrid / 32) + k) * 32 + c];
  s_red[r0][c] = s;
  __syncthreads();
  if (tid < 32) {
    float t = 0.f;
    for (int r = 0; r < 32; ++r) t += s_red[r][tid];
    s_final[tid] = t;
  }
  __syncthreads();
  if (tid == 0) {
    double acc = 0.0;
    for (int e = 0; e < kE; ++e)
      acc += (double)s_final[e] * (double)s_final[kE + e];
    out_aux[0] = (float)(acc * (double)kE / ((double)kB * (double)kB * (double)kS));
  }
}

extern "C" void kernel_launch(void* const* d_in, const int* in_sizes, int n_in,
                              void* d_out, int out_size, void* d_ws, size_t ws_size,
                              hipStream_t stream) {
  const float* x = (const float*)d_in[0];   // [B,S,H] f32
  const float* W = (const float*)d_in[1];   // [E,H]   f32
  float* out = (float*)d_out;               // [32768 probs][32768 idx][1 aux]
  float* gpart = (float*)d_ws;              // [kGrid][32], fully overwritten

  router_main<<<kGrid, kThreads, 0, stream>>>(
      x, W, out, out + 2 * kTokens, gpart);
  aux_finish<<<1, 1024, 0, stream>>>(gpart, out + 4 * kTokens);
}

// Round 5
// 88.114 us; speedup vs baseline: 3.0543x; 1.2252x over previous
//
#include <hip/hip_runtime.h>
#include <math.h>

namespace {
constexpr int kB = 4;
constexpr int kS = 4096;
constexpr int kH = 4096;
constexpr int kE = 16;
constexpr int kTokens = kB * kS;            // 16384
constexpr int kT = 4;                       // tokens per wave tile
constexpr int kEW = 8;                      // experts per wave tile (e-split 2)
constexpr int kThreads = 256;               // 4 waves: 2 token-groups x 2 e-halves
constexpr int kTokBlk = 8;                  // tokens per block
constexpr int kGrid = kTokens / kTokBlk;    // 2048
constexpr int kChunk = 256;                 // floats of H per j-iter (float4/lane)
constexpr int kNC = kH / kChunk;            // 16
}  // namespace

// Pure-streaming gate GEMM: x float4 direct from HBM (zero reuse -> no LDS),
// W float4 direct from XCD-L2 (256 KB, resident after warmup). No barriers or
// staging in the main loop; TLP (20 waves/CU) hides all latency.
__global__ __launch_bounds__(kThreads) void router_main(
    const float* __restrict__ x, const float* __restrict__ W,
    float* __restrict__ out_probs,   // [kTokens][2]
    float* __restrict__ out_idx,     // [kTokens][2] (indices as float)
    float* __restrict__ gpart) {     // [kGrid][32]: cnt[16], psum[16] per block
  __shared__ float s_logit[kTokBlk][kE];
  __shared__ float s_cnt[kE];
  __shared__ float s_psum[kE];

  const int tid = threadIdx.x;
  const int wave = tid >> 6;
  const int lane = tid & 63;
  const int tg = wave >> 1;                 // token group: 0 or 1
  const int eo = (wave & 1) * kEW;          // expert offset: 0 or 8
  const int tokBase = blockIdx.x * kTokBlk;
  const int tok0 = tokBase + tg * kT;

  if (tid < kE) { s_cnt[tid] = 0.f; s_psum[tid] = 0.f; }

  const float* xb = x + (size_t)tok0 * kH + lane * 4;
  const float* wb = W + (size_t)eo * kH + lane * 4;

  float acc[kT][kEW];
#pragma unroll
  for (int t = 0; t < kT; ++t)
#pragma unroll
    for (int e = 0; e < kEW; ++e) acc[t][e] = 0.f;

  for (int j = 0; j < kNC; ++j) {
    const size_t off = (size_t)j * kChunk;
    float4 xv[kT];
#pragma unroll
    for (int t = 0; t < kT; ++t)
      xv[t] = *reinterpret_cast<const float4*>(xb + (size_t)t * kH + off);
    float4 wv[kEW];
#pragma unroll
    for (int e = 0; e < kEW; ++e)
      wv[e] = *reinterpret_cast<const float4*>(wb + (size_t)e * kH + off);
#pragma unroll
    for (int e = 0; e < kEW; ++e)
#pragma unroll
      for (int t = 0; t < kT; ++t) {
        acc[t][e] = fmaf(xv[t].x, wv[e].x, acc[t][e]);
        acc[t][e] = fmaf(xv[t].y, wv[e].y, acc[t][e]);
        acc[t][e] = fmaf(xv[t].z, wv[e].z, acc[t][e]);
        acc[t][e] = fmaf(xv[t].w, wv[e].w, acc[t][e]);
      }
  }

  // Butterfly: every lane ends with full-H sums for its 4x8 tile.
#pragma unroll
  for (int off = 1; off < 64; off <<= 1) {
#pragma unroll
    for (int t = 0; t < kT; ++t)
#pragma unroll
      for (int e = 0; e < kEW; ++e)
        acc[t][e] += __shfl_xor(acc[t][e], off, 64);
  }

  // Lanes 0..3 of each wave publish their token's 8-expert slice.
  if (lane < kT) {
    const int r = tg * kT + lane;
#pragma unroll
    for (int e = 0; e < kEW; ++e) s_logit[r][eo + e] = acc[lane][e];
  }
  __syncthreads();

  // Wave 0, lanes 0..7: one token each — softmax, top-2, outputs, aux partials.
  if (wave == 0 && lane < kTokBlk) {
    const int tok = tokBase + lane;
    float l[kE];
#pragma unroll
    for (int e = 0; e < kE; ++e) l[e] = s_logit[lane][e];

    float m = l[0];
#pragma unroll
    for (int e = 1; e < kE; ++e) m = fmaxf(m, l[e]);
    float p[kE];
    float s = 0.f;
#pragma unroll
    for (int e = 0; e < kE; ++e) { p[e] = __expf(l[e] - m); s += p[e]; }
    const float inv = 1.f / s;
#pragma unroll
    for (int e = 0; e < kE; ++e) p[e] *= inv;

    // top-2 on probs (reference: top_k AFTER softmax; ties -> lowest index)
    int i1 = 0;
    float v1 = p[0];
#pragma unroll
    for (int e = 1; e < kE; ++e)
      if (p[e] > v1) { v1 = p[e]; i1 = e; }
    int i2 = (i1 == 0) ? 1 : 0;
    float v2 = p[i2];
#pragma unroll
    for (int e = 0; e < kE; ++e) {
      if (e == i1) continue;
      if (p[e] > v2) { v2 = p[e]; i2 = e; }
    }

    const float ns = 1.f / (v1 + v2);
    out_probs[tok * 2 + 0] = v1 * ns;
    out_probs[tok * 2 + 1] = v2 * ns;
    out_idx[tok * 2 + 0] = (float)i1;
    out_idx[tok * 2 + 1] = (float)i2;

#pragma unroll
    for (int e = 0; e < kE; ++e) atomicAdd(&s_psum[e], p[e]);
    atomicAdd(&s_cnt[i1], 1.f);
    atomicAdd(&s_cnt[i2], 1.f);
  }
  __syncthreads();
  // Per-block partials (coalesced store); reduced by aux_finish.
  if (tid < 2 * kE)
    gpart[(size_t)blockIdx.x * 2 * kE + tid] =
        (tid < kE) ? s_cnt[tid] : s_psum[tid - kE];
}

// Reduce per-block partials; aux = E * sum_e (cnt_e/B) * (psum_e/(B*S)).
__global__ __launch_bounds__(1024) void aux_finish(
    const float* __restrict__ gpart, float* __restrict__ out_aux) {
  __shared__ float s_red[32][32];
  __shared__ float s_final[32];
  const int tid = threadIdx.x;
  const int c = tid & 31;       // column: 0-15 cnt, 16-31 psum
  const int r0 = tid >> 5;      // row-slice 0..31
  float s = 0.f;
  for (int k = 0; k < kGrid / 32; ++k)
    s += gpart[(size_t)(r0 * (kGrid / 32) + k) * 32 + c];
  s_red[r0][c] = s;
  __syncthreads();
  if (tid < 32) {
    float t = 0.f;
    for (int r = 0; r < 32; ++r) t += s_red[r][tid];
    s_final[tid] = t;
  }
  __syncthreads();
  if (tid == 0) {
    double acc = 0.0;
    for (int e = 0; e < kE; ++e)
      acc += (double)s_final[e] * (double)s_final[kE + e];
    out_aux[0] = (float)(acc * (double)kE / ((double)kB * (double)kB * (double)kS));
  }
}

extern "C" void kernel_launch(void* const* d_in, const int* in_sizes, int n_in,
                              void* d_out, int out_size, void* d_ws, size_t ws_size,
                              hipStream_t stream) {
  const float* x = (const float*)d_in[0];   // [B,S,H] f32
  const float* W = (const float*)d_in[1];   // [E,H]   f32
  float* out = (float*)d_out;               // [32768 probs][32768 idx][1 aux]
  float* gpart = (float*)d_ws;              // [kGrid][32], fully overwritten

  router_main<<<kGrid, kThreads, 0, stream>>>(
      x, W, out, out + 2 * kTokens, gpart);
  aux_finish<<<1, 1024, 0, stream>>>(gpart, out + 4 * kTokens);
}